// Round 5
// baseline (5850.084 us; speedup 1.0000x reference)
//
#include <hip/hip_runtime.h>
#include <stdint.h>

// FPS: B=16, C=3, N=131072, M=2048. 256 blocks (16/batch) x 1024 thr, 1/CU.
// R5 vs R4 (DS-pipe arithmetic: R4 compute phase was LDS-issue-bound):
//  - ds_read_b128 data path: thread owns 2 groups of 4 consecutive points
//    (lane-stride 16 B, m97-verified conflict-free) -> 96 instead of 384
//    DS instrs/CU/iter for the distance update.
//  - Key dump-reduce: every thread ds_write_b64's its packed key; wave0
//    reads 1024 keys as b128 + tournament. Replaces 16 parallel u64
//    shuffle-butterflies (192 DS ops -> ~40).
//  - Winner COORDS ride in the barrier slots (4 self-tagged u64/block:
//    key,x,y,z). Centroid comes from the poll via shfl -> no px[sel]
//    global gather on the critical path; `sel` eliminated entirely.
//  - 2-deep pipelined poll (detect granularity ~loop body, not RTT).
// Numerics (bit-matches ref, verified R2): d = fma(dz,dz, fma(dy,dy, dx*dx)).

#define NBATCH    16
#define NPTS      131072
#define SUBBLOCKS 16
#define NTHREADS  1024
#define CHUNK     8192          // points per block
#define HALF      4096          // group stride (2 groups of 4 pts per thread)
#define SLOTW     4             // u64 words per block slot: key,x,y,z

typedef unsigned long long u64;

__device__ __forceinline__ u64 umax64(u64 a, u64 b) { return a > b ? a : b; }

__global__ __launch_bounds__(NTHREADS, 4)
void fps_kernel(const float* __restrict__ points,
                float* __restrict__ out,
                u64* __restrict__ slots, int M)
{
  __shared__ __align__(16) float xs[CHUNK];
  __shared__ __align__(16) float ys[CHUNK];
  __shared__ __align__(16) float zs[CHUNK];
  __shared__ __align__(16) u64  keys[NTHREADS];
  __shared__ __align__(16) float bc[4];          // cx, cy, cz, pad

  const int bid   = blockIdx.x;
  const int xcd   = bid & 7;                     // XCD swizzle (speed only)
  const int ord   = bid >> 3;
  const int batch = xcd * 2 + (ord >> 4);
  const int sub   = ord & 15;
  const int tid   = threadIdx.x;
  const int wave  = tid >> 6;
  const int lane  = tid & 63;

  const float* __restrict__ px = points + (size_t)batch * 3 * NPTS;
  const float* __restrict__ py = px + NPTS;
  const float* __restrict__ pz = px + 2 * NPTS;
  float* outb = out + (size_t)batch * 3 * M;
  u64* bslots = slots + (size_t)batch * 2 * SUBBLOCKS * SLOTW;

  const int cbase = sub * CHUNK;

  // Stage chunk into LDS; layout matches the b128 read pattern below.
  {
    int o0 = tid * 4, o1 = HALF + tid * 4;
    *(float4*)(xs + o0) = *(const float4*)(px + cbase + o0);
    *(float4*)(ys + o0) = *(const float4*)(py + cbase + o0);
    *(float4*)(zs + o0) = *(const float4*)(pz + cbase + o0);
    *(float4*)(xs + o1) = *(const float4*)(px + cbase + o1);
    *(float4*)(ys + o1) = *(const float4*)(py + cbase + o1);
    *(float4*)(zs + o1) = *(const float4*)(pz + cbase + o1);
  }

  float d0, d1, d2, d3, d4, d5, d6, d7;
  d0 = d1 = d2 = d3 = d4 = d5 = d6 = d7 = __builtin_inff();

  // Centroid 0 = point 0 (one-time global broadcast read).
  float cx = px[0], cy = py[0], cz = pz[0];
  if (sub == 0 && tid == 0) { outb[0] = cx; outb[M] = cy; outb[2 * M] = cz; }

  __syncthreads();   // staging complete

  for (int t = 1; t < M; ++t) {
    // ---- distance update + per-thread argmax (6x ds_read_b128) ----
    const float4 X0 = *(const float4*)(xs + (tid << 2));
    const float4 Y0 = *(const float4*)(ys + (tid << 2));
    const float4 Z0 = *(const float4*)(zs + (tid << 2));
    const float4 X1 = *(const float4*)(xs + HALF + (tid << 2));
    const float4 Y1 = *(const float4*)(ys + HALF + (tid << 2));
    const float4 Z1 = *(const float4*)(zs + HALF + (tid << 2));

    float best = -1.0f;
    int bidx = 0;
    // d = fma(dz,dz, fma(dy,dy, dx*dx)) : bit-matches the reference chain.
    // Traversal order ascending in global index => strict '>' keeps first max.
#define STEP(PX, PY, PZ, DREG, IDX) { \
    float dx = __fsub_rn((PX), cx); \
    float dy = __fsub_rn((PY), cy); \
    float dz = __fsub_rn((PZ), cz); \
    float dd = __builtin_fmaf(dz, dz, __builtin_fmaf(dy, dy, __fmul_rn(dx, dx))); \
    DREG = DREG < dd ? DREG : dd; \
    if (DREG > best) { best = DREG; bidx = (IDX); } }
    STEP(X0.x, Y0.x, Z0.x, d0, cbase + (tid << 2) + 0)
    STEP(X0.y, Y0.y, Z0.y, d1, cbase + (tid << 2) + 1)
    STEP(X0.z, Y0.z, Z0.z, d2, cbase + (tid << 2) + 2)
    STEP(X0.w, Y0.w, Z0.w, d3, cbase + (tid << 2) + 3)
    STEP(X1.x, Y1.x, Z1.x, d4, cbase + HALF + (tid << 2) + 0)
    STEP(X1.y, Y1.y, Z1.y, d5, cbase + HALF + (tid << 2) + 1)
    STEP(X1.z, Y1.z, Z1.z, d6, cbase + HALF + (tid << 2) + 2)
    STEP(X1.w, Y1.w, Z1.w, d7, cbase + HALF + (tid << 2) + 3)

    // Pack [distBits:32 @17][invIdx:17 @0]; invIdx = smaller global index wins ties.
    keys[tid] = ((u64)__float_as_uint(best) << 17) | (u64)((NPTS - 1) - bidx);
    __syncthreads();   // dump complete

    if (wave == 0) {
      // Tournament over all 1024 keys: 8x b128 reads (2 keys each).
      u64 k = 0;
#pragma unroll
      for (int j = 0; j < 8; ++j) {
        ulonglong2 kk = *(const ulonglong2*)(keys + (lane << 1) + (j << 7));
        k = umax64(k, umax64(kk.x, kk.y));
      }
#pragma unroll
      for (int m = 32; m >= 1; m >>= 1) {
        u64 o = __shfl_xor(k, m, 64);
        k = umax64(k, o);
      }
      // Publish block winner: key + its coords (from our LDS chunk), each
      // word self-tagged so the poll validates per-word (stores may land
      // in any order; relaxed agent atomics suffice).
      u64* par = bslots + (size_t)(t & 1) * SUBBLOCKS * SLOTW;
      if (lane == 0) {
        int loc = ((NPTS - 1) - (int)(k & 0x1FFFF)) - cbase;   // 0..8191
        u64* myp = par + sub * SLOTW;
        __hip_atomic_store(myp + 0, ((u64)t << 49) | k,
                           __ATOMIC_RELAXED, __HIP_MEMORY_SCOPE_AGENT);
        __hip_atomic_store(myp + 1, ((u64)t << 32) | (u64)__float_as_uint(xs[loc]),
                           __ATOMIC_RELAXED, __HIP_MEMORY_SCOPE_AGENT);
        __hip_atomic_store(myp + 2, ((u64)t << 32) | (u64)__float_as_uint(ys[loc]),
                           __ATOMIC_RELAXED, __HIP_MEMORY_SCOPE_AGENT);
        __hip_atomic_store(myp + 3, ((u64)t << 32) | (u64)__float_as_uint(zs[loc]),
                           __ATOMIC_RELAXED, __HIP_MEMORY_SCOPE_AGENT);
      }
      // Converged poll: lane L reads word L of the 64-word (512 B) region.
      // 2-deep pipelined: detect granularity ~ loop body, not full RTT.
      const int w = lane & 3;
      const unsigned shift = (w == 0) ? 49u : 32u;
      u64 va = __hip_atomic_load(par + lane, __ATOMIC_RELAXED, __HIP_MEMORY_SCOPE_AGENT);
      u64 vb = __hip_atomic_load(par + lane, __ATOMIC_RELAXED, __HIP_MEMORY_SCOPE_AGENT);
      u64 v;
      for (;;) {
        bool ok = (unsigned)(va >> shift) == (unsigned)t;
        if (__ballot(ok) == ~0ull) { v = va; break; }
        va = vb;
        vb = __hip_atomic_load(par + lane, __ATOMIC_RELAXED, __HIP_MEMORY_SCOPE_AGENT);
      }
      // Reduce the 16 key-words (class lanes L%4==0); raw compare valid
      // (equal tags). Strides 4..32 keep the class closed.
      u64 k2 = (w == 0) ? v : 0;
#pragma unroll
      for (int m = 4; m <= 32; m <<= 1) {
        u64 o = __shfl_xor(k2, m, 64);
        k2 = umax64(k2, o);
      }
      // Winner block id -> pull its coord words via shfl (index garbage on
      // non-class lanes is harmless; lane 0's is correct).
      int selg = (NPTS - 1) - (int)(k2 & 0x1FFFF);
      int wb   = selg >> 13;
      u64 xw = __shfl(v, wb * 4 + 1, 64);
      u64 yw = __shfl(v, wb * 4 + 2, 64);
      u64 zw = __shfl(v, wb * 4 + 3, 64);
      if (lane == 0) {
        bc[0] = __uint_as_float((unsigned)xw);
        bc[1] = __uint_as_float((unsigned)yw);
        bc[2] = __uint_as_float((unsigned)zw);
      }
    }
    __syncthreads();   // winner broadcast

    float4 c = *(const float4*)bc;   // LDS broadcast read
    cx = c.x; cy = c.y; cz = c.z;

    if (sub == 0 && tid == 0) {
      outb[t]         = cx;
      outb[M + t]     = cy;
      outb[2 * M + t] = cz;
    }
  }
}

extern "C" void kernel_launch(void* const* d_in, const int* in_sizes, int n_in,
                              void* d_out, int out_size, void* d_ws, size_t ws_size,
                              hipStream_t stream) {
  (void)in_sizes; (void)n_in; (void)ws_size;
  const float* points = (const float*)d_in[0];
  float* out = (float*)d_out;
  u64* slots = (u64*)d_ws;
  const int M = out_size / (NBATCH * 3);   // 2048

  // Zero barrier slots (stale tags must not alias t in 1..M-1): 16 KB.
  hipMemsetAsync(d_ws, 0,
                 (size_t)NBATCH * 2 * SUBBLOCKS * SLOTW * sizeof(u64), stream);

  hipLaunchKernelGGL(fps_kernel, dim3(NBATCH * SUBBLOCKS), dim3(NTHREADS), 0,
                     stream, points, out, slots, M);
}

// Round 6
// 4125.263 us; speedup vs baseline: 1.4181x; 1.4181x over previous
//
#include <hip/hip_runtime.h>
#include <stdint.h>

// FPS: B=16, C=3, N=131072, M=2048. 256 blocks (16/batch) x 1024 thr, 1/CU.
//
// R6 = R4's verified-best protocol + register-resident coordinates.
//  - R5 post-mortem: 4-word self-tagged slots quadrupled barrier fabric
//    traffic (WRITE 16.7->65.9 MB, FETCH 15->48 MB) and the wave0-serial
//    tournament idled 15/16 waves (VALUBusy 31.6->14.4%). Reverted both:
//    1 key-word/block, one 128 B poll line/batch, per-wave parallel
//    butterflies, centroid via px[sel] (L2-hot broadcast).
//  - New: all 24 coord floats pinned in VGPRs via empty asm("+v") so the
//    compiler cannot sink the loads back into the loop (R2/R3 showed it
//    rematerializes otherwise: VGPR_Count=32). Eliminates the per-iter
//    24x ds_read_b32 (~0.93 us/iter DS issue in R4). LDS now only holds
//    wkeys + winner (no 96 KB staging at all).
// Numerics (bit-matches XLA-CPU ref, verified R2/R4/R5):
//   d = fma(dz,dz, fma(dy,dy, dx*dx)); first-occurrence argmax via
//   packed key [distBits:32][invIdx:17], tag at bit 49.

#define NBATCH    16
#define NPTS      131072
#define SUBBLOCKS 16
#define NTHREADS  1024
#define CHUNK     8192          // points per block
#define HALF      4096          // second group offset within chunk

typedef unsigned long long u64;

__device__ __forceinline__ u64 umax64(u64 a, u64 b) { return a > b ? a : b; }

__global__ __launch_bounds__(NTHREADS, 4)
void fps_kernel(const float* __restrict__ points,
                float* __restrict__ out,
                u64* __restrict__ slots, int M)
{
  __shared__ u64 wkeys[NTHREADS / 64];
  __shared__ u64 winner_s;

  const int bid   = blockIdx.x;
  const int xcd   = bid & 7;                 // XCD swizzle (speed only)
  const int ord   = bid >> 3;
  const int batch = xcd * 2 + (ord >> 4);
  const int sub   = ord & 15;
  const int tid   = threadIdx.x;
  const int wave  = tid >> 6;
  const int lane  = tid & 63;

  const float* __restrict__ px = points + (size_t)batch * 3 * NPTS;
  const float* __restrict__ py = px + NPTS;
  const float* __restrict__ pz = px + 2 * NPTS;
  float* outb = out + (size_t)batch * 3 * M;
  u64* bslots = slots + (size_t)batch * 2 * SUBBLOCKS;

  const int cbase = sub * CHUNK;
  const int g0 = cbase + (tid << 2);         // global idx of first group
  const int g1 = g0 + HALF;                  // global idx of second group

  // Load this thread's 8 points (2 x float4 per coord plane, coalesced).
  float4 A0 = *(const float4*)(px + g0);
  float4 B0 = *(const float4*)(py + g0);
  float4 C0 = *(const float4*)(pz + g0);
  float4 A1 = *(const float4*)(px + g1);
  float4 B1 = *(const float4*)(py + g1);
  float4 C1 = *(const float4*)(pz + g1);
  float x0=A0.x, x1=A0.y, x2=A0.z, x3=A0.w, x4=A1.x, x5=A1.y, x6=A1.z, x7=A1.w;
  float y0=B0.x, y1=B0.y, y2=B0.z, y3=B0.w, y4=B1.x, y5=B1.y, y6=B1.z, y7=B1.w;
  float z0=C0.x, z1=C0.y, z2=C0.z, z3=C0.w, z4=C1.x, z5=C1.y, z6=C1.z, z7=C1.w;
  // Pin all 24 coords in VGPRs: opaque to the optimizer => cannot be
  // rematerialized from memory inside the loop (the R2/R3 sink failure).
  asm volatile("" :
    "+v"(x0),"+v"(x1),"+v"(x2),"+v"(x3),"+v"(x4),"+v"(x5),"+v"(x6),"+v"(x7),
    "+v"(y0),"+v"(y1),"+v"(y2),"+v"(y3),"+v"(y4),"+v"(y5),"+v"(y6),"+v"(y7),
    "+v"(z0),"+v"(z1),"+v"(z2),"+v"(z3),"+v"(z4),"+v"(z5),"+v"(z6),"+v"(z7));

  float d0, d1, d2, d3, d4, d5, d6, d7;
  d0 = d1 = d2 = d3 = d4 = d5 = d6 = d7 = __builtin_inff();

  // Selection 0 is index 0 by convention.
  if (sub == 0 && tid == 0) {
    outb[0]     = px[0];
    outb[M]     = py[0];
    outb[2 * M] = pz[0];
  }

  int sel = 0;
  for (int t = 1; t < M; ++t) {
    // Centroid = previously selected point (uniform broadcast loads, L2-hot).
    float cx = px[sel], cy = py[sel], cz = pz[sel];

    float best = -1.0f;
    int bidx = 0;
    // d = fma(dz,dz, fma(dy,dy, dx*dx)) : bit-matches the reference chain.
    // Ascending index order => strict '>' keeps the first (smallest) index.
#define STEP(XX, YY, ZZ, DREG, IDX) { \
    float dx = __fsub_rn((XX), cx); \
    float dy = __fsub_rn((YY), cy); \
    float dz = __fsub_rn((ZZ), cz); \
    float dd = __builtin_fmaf(dz, dz, __builtin_fmaf(dy, dy, __fmul_rn(dx, dx))); \
    DREG = DREG < dd ? DREG : dd; \
    if (DREG > best) { best = DREG; bidx = (IDX); } }
    STEP(x0, y0, z0, d0, g0 + 0)
    STEP(x1, y1, z1, d1, g0 + 1)
    STEP(x2, y2, z2, d2, g0 + 2)
    STEP(x3, y3, z3, d3, g0 + 3)
    STEP(x4, y4, z4, d4, g1 + 0)
    STEP(x5, y5, z5, d5, g1 + 1)
    STEP(x6, y6, z6, d6, g1 + 2)
    STEP(x7, y7, z7, d7, g1 + 3)

    // Pack [distBits:32 @17][invIdx:17 @0]; non-negative f32 bits are
    // order-preserving; invIdx breaks ties toward the SMALLEST index.
    u64 key = ((u64)__float_as_uint(best) << 17) | (u64)((NPTS - 1) - bidx);

    // Per-wave butterfly (parallel across all 16 waves).
#pragma unroll
    for (int m = 32; m >= 1; m >>= 1) {
      u64 o = __shfl_xor(key, m, 64);
      key = umax64(key, o);
    }
    if (lane == 0) wkeys[wave] = key;
    __syncthreads();

    if (wave == 0) {
      // Block reduce: lanes mirror wkeys[lane&15] (same-address broadcasts
      // are free), 4-step butterfly.
      u64 k = wkeys[lane & 15];
#pragma unroll
      for (int m = 8; m >= 1; m >>= 1) {
        u64 o = __shfl_xor(k, m, 64);
        k = umax64(k, o);
      }
      // Publish tagged block winner: ONE u64/block, 16 slots = one 128 B
      // line per batch (R5 showed bigger footprints explode fabric traffic).
      u64* par = bslots + (size_t)(t & 1) * SUBBLOCKS;
      if (lane == 0) {
        __hip_atomic_store(par + sub, ((u64)t << 49) | k,
                           __ATOMIC_RELAXED, __HIP_MEMORY_SCOPE_AGENT);
      }
      // Converged poll: every lane reads slot (lane&15) -> one coalesced
      // 128 B line per round; exit only when ALL tags match t.
      const u64* pp = par + (lane & 15);
      u64 v;
      for (;;) {
        v = __hip_atomic_load(pp, __ATOMIC_RELAXED, __HIP_MEMORY_SCOPE_AGENT);
        if (__ballot((unsigned)(v >> 49) == (unsigned)t) == ~0ull) break;
      }
#pragma unroll
      for (int m = 8; m >= 1; m >>= 1) {
        u64 o = __shfl_xor(v, m, 64);
        v = umax64(v, o);
      }
      if (lane == 0) winner_s = v;
    }
    __syncthreads();

    sel = (NPTS - 1) - (int)(winner_s & 0x1FFFF);

    if (sub == 0 && tid == 0) {
      outb[t]         = px[sel];
      outb[M + t]     = py[sel];
      outb[2 * M + t] = pz[sel];
    }
  }
}

extern "C" void kernel_launch(void* const* d_in, const int* in_sizes, int n_in,
                              void* d_out, int out_size, void* d_ws, size_t ws_size,
                              hipStream_t stream) {
  (void)in_sizes; (void)n_in; (void)ws_size;
  const float* points = (const float*)d_in[0];
  float* out = (float*)d_out;
  u64* slots = (u64*)d_ws;
  const int M = out_size / (NBATCH * 3);   // 2048

  // Zero barrier slots (stale tags must not alias t in 1..M-1).
  hipMemsetAsync(d_ws, 0, (size_t)NBATCH * 2 * SUBBLOCKS * sizeof(u64), stream);

  hipLaunchKernelGGL(fps_kernel, dim3(NBATCH * SUBBLOCKS), dim3(NTHREADS), 0,
                     stream, points, out, slots, M);
}